// Round 12
// baseline (473.803 us; speedup 1.0000x reference)
//
#include <hip/hip_runtime.h>
#include <math.h>

#define N_NODES 4096
#define N_EDGES 131072
#define XPAD    272   // bf16 elems per LDS row: stride 544B = 136 words ≡ 8 mod 32 per
                      // 16-row step -> uniform-floor banking for b128 reads

using bf16x8 = __attribute__((ext_vector_type(8))) __bf16;
using f32x4  = __attribute__((ext_vector_type(4))) float;
typedef unsigned short u16;

__device__ __forceinline__ u16 f2bf(float f) {
  union { __bf16 b; u16 u; } cv; cv.b = (__bf16)f; return cv.u;
}
__device__ __forceinline__ float bf2f(u16 h) {
  return __uint_as_float(((unsigned)h) << 16);
}
// tanh-form GELU (max err ~3e-4 vs exact; margin 0.0156 vs 0.0963 threshold)
__device__ __forceinline__ float gelu_tanh(float x) {
  float t = x * x;
  float y = x * (1.5957691216057308f + 0.07135481627f * t);
  float e = __expf(y);
  return x - x / (1.0f + e);
}
__device__ __forceinline__ f32x4 mfma16(bf16x8 a, bf16x8 b, f32x4 c) {
  return __builtin_amdgcn_mfma_f32_16x16x32_bf16(a, b, c, 0, 0, 0);
}

struct WPtrs { const float* p[10]; };
struct OPtrs { float* o[4]; float* l; };

// ---------------- setup: pack weights (coalesced) + hist + qkv bias -------------
__global__ void setup_kernel(WPtrs w, u16* __restrict__ dst, float qscale,
                             const int* __restrict__ ei, int* __restrict__ deg,
                             const float* __restrict__ bq, const float* __restrict__ bk,
                             const float* __restrict__ bv, float* __restrict__ qkvbias) {
  int blk = blockIdx.x, t = threadIdx.x;
  if (blk < 512) {
    int tid = blk * 256 + t;
    int m, ci;
    if (tid < 32768)      { m = tid >> 13;                 ci = tid & 8191; }
    else if (tid < 57344) { m = 4 + ((tid - 32768) >> 13); ci = (tid - 32768) & 8191; }
    else if (tid < 65536) { m = 7; ci = tid - 57344; }
    else if (tid < 98304) { m = 8; ci = tid - 65536; }
    else                  { m = 9; ci = tid - 98304; }
    int Cols = (m == 8) ? 1024 : 256;
    int k8   = (m == 8) ? (ci >> 10) : (ci >> 8);
    int c    = (m == 8) ? (ci & 1023) : (ci & 255);
    const float* src = w.p[m] + (size_t)(k8 * 8) * Cols + c;
    float sc = (m == 4) ? qscale : 1.0f;
    u16 tmp[8];
#pragma unroll
    for (int j = 0; j < 8; ++j) tmp[j] = f2bf(src[(size_t)j * Cols] * sc);
    size_t off;
    if (m < 4)       off = (size_t)(m << 16) + (size_t)(k8 * 256 + c) * 8;
    else if (m < 7)  off = 262144 + (size_t)(k8 * 768 + (m - 4) * 256 + c) * 8;
    else if (m == 7) off = 458752 + (size_t)(k8 * 256 + c) * 8;
    else if (m == 8) off = 524288 + (size_t)(k8 * 1024 + c) * 8;
    else             off = 786432 + (size_t)(k8 * 256 + c) * 8;
    *(uint4*)(dst + off) = *(const uint4*)tmp;
  } else if (blk < 1024) {
    int e = (blk - 512) * 256 + t;
    atomicAdd(&deg[ei[N_EDGES + e]], 1);
  } else {
#pragma unroll
    for (int i = 0; i < 3; ++i) {
      int idx = i * 256 + t;
      qkvbias[idx] = idx < 256 ? bq[idx] * qscale : (idx < 512 ? bk[idx - 256] : bv[idx - 512]);
    }
  }
}

// ---------------- LN_local (4 rows/block) + scan fused --------------------------
__global__ void ln_scan_kernel(const float* __restrict__ x, const float* __restrict__ g,
                               const float* __restrict__ b, float* __restrict__ hf,
                               u16* __restrict__ hb, const int* __restrict__ deg,
                               int* __restrict__ offs) {
  int blk = blockIdx.x, t = threadIdx.x;
  if (blk < 1024) {
    int row = blk * 4 + (t >> 8);
    int c = t & 255;
    float v = x[(size_t)row * 256 + c];
    float s1 = v, s2 = v * v;
#pragma unroll
    for (int o = 32; o > 0; o >>= 1) { s1 += __shfl_xor(s1, o); s2 += __shfl_xor(s2, o); }
    __shared__ float a1[16], a2[16];
    int wv = t >> 6;                  // 0..15; each row owns waves 4r..4r+3
    if ((t & 63) == 0) { a1[wv] = s1; a2[wv] = s2; }
    __syncthreads();
    int rg = (t >> 8) * 4;
    s1 = a1[rg] + a1[rg + 1] + a1[rg + 2] + a1[rg + 3];
    s2 = a2[rg] + a2[rg + 1] + a2[rg + 2] + a2[rg + 3];
    float mean = s1 * (1.0f / 256.0f);
    float var  = s2 * (1.0f / 256.0f) - mean * mean;
    float rs = rsqrtf(var + 1e-5f);
    float o = (v - mean) * rs * g[c] + b[c];
    hf[(size_t)row * 256 + c] = o;
    hb[(size_t)row * 256 + c] = f2bf(o);
  } else {
    __shared__ int part[1024];
    int base = t * 4;
    int a0 = deg[base], a1v = deg[base + 1], a2v = deg[base + 2], a3 = deg[base + 3];
    int s = a0 + a1v + a2v + a3;
    part[t] = s;
    __syncthreads();
    for (int off = 1; off < 1024; off <<= 1) {
      int v = (t >= off) ? part[t - off] : 0;
      __syncthreads();
      part[t] += v;
      __syncthreads();
    }
    int excl = part[t] - s;
    offs[base] = excl;
    offs[base + 1] = excl + a0;
    offs[base + 2] = excl + a0 + a1v;
    offs[base + 3] = excl + a0 + a1v + a2v;
    if (t == 1023) offs[4096] = part[1023];
  }
}

// ---------------- scatter (counting-sort placement) -----------------------------
__global__ void scatter_kernel(const int* __restrict__ ei, const int* __restrict__ offs,
                               int* __restrict__ cnt, int* __restrict__ eperm,
                               int* __restrict__ dst_s, int* __restrict__ src_s) {
  int e = blockIdx.x * 256 + threadIdx.x;
  int d = ei[N_EDGES + e];
  int p = offs[d] + atomicAdd(&cnt[d], 1);
  eperm[p] = e;
  dst_s[p] = d;
  src_s[p] = ei[e];
}

// ---------------- fused edge MLP + in-block segment sum -------------------------
// 512 threads = 8 waves (2 row-halves x 4 col-quarters) over a 128-edge tile.
// Segment sum: edges are dst-sorted, group list via ballot compaction; fully
// contained groups use plain stores, boundary groups atomicAdd.
// Journal: R2 more-waves null; R3 atomic fix -14us; R4 reg-pipelining spilled
// (570MB scratch); R6 64-tile 4blk/CU occupancy 50% REGRESSED (+8us) -- the
// ~99us is intra-block serial VALU+barrier cost, not parallelism-starvation.
// This is the known-best R5 form.
__launch_bounds__(512, 4)
__global__ void edge_kernel(const u16* __restrict__ hb, const float* __restrict__ ea,
                            const int* __restrict__ eperm, const int* __restrict__ src_s,
                            const int* __restrict__ dst_s, const int* __restrict__ offs,
                            const u16* __restrict__ wp1, const float* __restrict__ b1,
                            const u16* __restrict__ wp2, const float* __restrict__ b2,
                            float* __restrict__ agg) {
  __shared__ __align__(16) u16 X[128 * XPAD];
  __shared__ int gstart[130];
  __shared__ unsigned long long bm[2];
  __shared__ int Gs;
  const f32x4 fzero = {0.f, 0.f, 0.f, 0.f};
  int t = threadIdx.x;
  int lane = t & 63, wv = t >> 6;
  int lr = lane & 15, lq = lane >> 4;
  int wr = wv >> 2, wc = wv & 3;      // row-half, col-quarter
  int e0 = blockIdx.x * 128;
  int col0 = wc * 64;
  int row0 = wr * 64;

  const u16* b1ptr = wp1 + ((size_t)lq * 256 + col0 + lr) * 8;
  const u16* b2ptr = wp2 + ((size_t)lq * 256 + col0 + lr) * 8;
  bf16x8 bc[4], bn[4];
#pragma unroll
  for (int ct = 0; ct < 4; ++ct) bc[ct] = *(const bf16x8*)(b1ptr + ct * 128);

  int ci = (t & 31) * 8;
#pragma unroll
  for (int it = 0; it < 8; ++it) {
    int r = it * 16 + (t >> 5);
    int e = eperm[e0 + r];
    int s = src_s[e0 + r];
    const float* pa = ea + (size_t)e * 256 + ci;
    float4 a0 = *(const float4*)pa;
    float4 a1 = *(const float4*)(pa + 4);
    ushort4 h0 = *(const ushort4*)(hb + (size_t)s * 256 + ci);
    ushort4 h1 = *(const ushort4*)(hb + (size_t)s * 256 + ci + 4);
    u16 tmp[8];
    tmp[0] = f2bf(a0.x + bf2f(h0.x)); tmp[1] = f2bf(a0.y + bf2f(h0.y));
    tmp[2] = f2bf(a0.z + bf2f(h0.z)); tmp[3] = f2bf(a0.w + bf2f(h0.w));
    tmp[4] = f2bf(a1.x + bf2f(h1.x)); tmp[5] = f2bf(a1.y + bf2f(h1.y));
    tmp[6] = f2bf(a1.z + bf2f(h1.z)); tmp[7] = f2bf(a1.w + bf2f(h1.w));
    *(uint4*)&X[r * XPAD + ci] = *(const uint4*)tmp;
  }
  // group-boundary flags for the 128 dst rows (waves 0,1 only)
  int flag = 0;
  if (t < 128) {
    int d  = dst_s[e0 + t];
    int dp = (t == 0) ? -1 : dst_s[e0 + t - 1];
    flag = (d != dp) ? 1 : 0;
  }
  unsigned long long m = __ballot(flag);
  if (wv < 2 && lane == 0) bm[wv] = m;
  __syncthreads();

  f32x4 acc[4][4];
#pragma unroll
  for (int i = 0; i < 4; ++i)
#pragma unroll
    for (int j = 0; j < 4; ++j) acc[i][j] = fzero;

  // ---- GEMM1 (pipelined B) ----
#pragma unroll
  for (int ks = 0; ks < 8; ++ks) {
    if (ks < 7) {
#pragma unroll
      for (int ct = 0; ct < 4; ++ct)
        bn[ct] = *(const bf16x8*)(b1ptr + (size_t)(ks + 1) * 8192 + ct * 128);
    }
    bf16x8 a[4];
#pragma unroll
    for (int rt = 0; rt < 4; ++rt)
      a[rt] = *(const bf16x8*)&X[(row0 + rt * 16 + lr) * XPAD + ks * 32 + lq * 8];
#pragma unroll
    for (int ct = 0; ct < 4; ++ct)
#pragma unroll
      for (int rt = 0; rt < 4; ++rt) acc[rt][ct] = mfma16(a[rt], bc[ct], acc[rt][ct]);
#pragma unroll
    for (int ct = 0; ct < 4; ++ct) bc[ct] = bn[ct];
  }
#pragma unroll
  for (int ct = 0; ct < 4; ++ct) bn[ct] = *(const bf16x8*)(b2ptr + ct * 128);
  // compaction: ordered group starts (uses bm written before GEMM1 barrier)
  if (t < 128 && flag) {
    int idx = __popcll(bm[wv] & ((1ull << lane) - 1));
    if (wv == 1) idx += __popcll(bm[0]);
    gstart[idx] = t;
  }
  if (t == 0) {
    int g = __popcll(bm[0]) + __popcll(bm[1]);
    Gs = g;
    gstart[g] = 128;
  }
  __syncthreads();

  // ---- GELU -> back to X ----
#pragma unroll
  for (int ct = 0; ct < 4; ++ct) {
    int c = col0 + ct * 16 + lr;
    float bb = b1[c];
#pragma unroll
    for (int rt = 0; rt < 4; ++rt)
#pragma unroll
      for (int r = 0; r < 4; ++r) {
        int row = row0 + rt * 16 + lq * 4 + r;
        X[row * XPAD + c] = f2bf(gelu_tanh(acc[rt][ct][r] + bb));
      }
  }
#pragma unroll
  for (int ct = 0; ct < 4; ++ct) bc[ct] = bn[ct];
  __syncthreads();

  // ---- GEMM2 (pipelined B) ----
#pragma unroll
  for (int i = 0; i < 4; ++i)
#pragma unroll
    for (int j = 0; j < 4; ++j) acc[i][j] = fzero;
#pragma unroll
  for (int ks = 0; ks < 8; ++ks) {
    if (ks < 7) {
#pragma unroll
      for (int ct = 0; ct < 4; ++ct)
        bn[ct] = *(const bf16x8*)(b2ptr + (size_t)(ks + 1) * 8192 + ct * 128);
    }
    bf16x8 a[4];
#pragma unroll
    for (int rt = 0; rt < 4; ++rt)
      a[rt] = *(const bf16x8*)&X[(row0 + rt * 16 + lr) * XPAD + ks * 32 + lq * 8];
#pragma unroll
    for (int ct = 0; ct < 4; ++ct)
#pragma unroll
      for (int rt = 0; rt < 4; ++rt) acc[rt][ct] = mfma16(a[rt], bc[ct], acc[rt][ct]);
#pragma unroll
    for (int ct = 0; ct < 4; ++ct) bc[ct] = bn[ct];
  }
  __syncthreads();

  // ---- msg (+bias) -> X as bf16 ----
#pragma unroll
  for (int ct = 0; ct < 4; ++ct) {
    int c = col0 + ct * 16 + lr;
    float bb = b2[c];
#pragma unroll
    for (int rt = 0; rt < 4; ++rt)
#pragma unroll
      for (int r = 0; r < 4; ++r) {
        int row = row0 + rt * 16 + lq * 4 + r;
        X[row * XPAD + c] = f2bf(acc[rt][ct][r] + bb);
      }
  }
  __syncthreads();

  // ---- segment sum: wave gi owns group gi; 64 lanes x 4 cols ----
  {
    int G = Gs;
    int c4 = lane * 4;
    for (int gi = wv; gi < G; gi += 8) {
      int rs = gstart[gi], re = gstart[gi + 1];
      int d = dst_s[e0 + rs];
      float run0 = 0.f, run1 = 0.f, run2 = 0.f, run3 = 0.f;
      for (int r = rs; r < re; ++r) {
        ushort4 xv = *(const ushort4*)&X[r * XPAD + c4];
        run0 += bf2f(xv.x); run1 += bf2f(xv.y); run2 += bf2f(xv.z); run3 += bf2f(xv.w);
      }
      bool full = (offs[d] == e0 + rs) && (offs[d + 1] == e0 + re);
      float* p = &agg[(size_t)d * 256 + c4];
      if (full) {
        *(float4*)p = make_float4(run0, run1, run2, run3);
      } else {
        atomicAdd(p + 0, run0); atomicAdd(p + 1, run1);
        atomicAdd(p + 2, run2); atomicAdd(p + 3, run3);
      }
    }
  }
}

// ---------------- fused node-update MLP + residual + LN_global ------------------
// 32-row tiles -> 128 blocks (was 64): at 64 blocks 3/4 of the GPU idled and
// duration ~ single-block serial chain. LDS 17KB, acc[2][4].
#define UROWS 32
__launch_bounds__(256, 4)
__global__ void update_kernel(const float* __restrict__ hf, const float* __restrict__ agg,
                              const float* __restrict__ epsp, const float* __restrict__ xin,
                              const u16* __restrict__ wp1, const float* __restrict__ b1,
                              const u16* __restrict__ wp2, const float* __restrict__ b2,
                              const float* __restrict__ lng, const float* __restrict__ lnb,
                              float* __restrict__ x1, u16* __restrict__ gb) {
  __shared__ __align__(16) u16 X[UROWS * XPAD];
  __shared__ float S1[UROWS][4], S2[UROWS][4], MUs[UROWS], RSs[UROWS];
  const f32x4 fzero = {0.f, 0.f, 0.f, 0.f};
  int t = threadIdx.x;
  int lane = t & 63, wv = t >> 6;
  int lr = lane & 15, lq = lane >> 4;
  int n0 = blockIdx.x * UROWS;
  int col0 = wv * 64;
  float epv = 1.0f + epsp[0];
  const u16* b1ptr = wp1 + ((size_t)lq * 256 + col0 + lr) * 8;
  const u16* b2ptr = wp2 + ((size_t)lq * 256 + col0 + lr) * 8;
  bf16x8 bc[4], bn[4];
#pragma unroll
  for (int ct = 0; ct < 4; ++ct) bc[ct] = *(const bf16x8*)(b1ptr + ct * 128);
  {
    int c4 = (t & 63) * 4;
#pragma unroll
    for (int ii = 0; ii < UROWS / 4; ++ii) {
      int r = ii * 4 + wv;
      float4 h = *(const float4*)(hf + (size_t)(n0 + r) * 256 + c4);
      float4 a = *(const float4*)(agg + (size_t)(n0 + r) * 256 + c4);
      *(ushort4*)&X[r * XPAD + c4] =
          make_ushort4(f2bf(epv * h.x + a.x), f2bf(epv * h.y + a.y),
                       f2bf(epv * h.z + a.z), f2bf(epv * h.w + a.w));
    }
  }
  __syncthreads();
  f32x4 acc[2][4];
#pragma unroll
  for (int i = 0; i < 2; ++i)
#pragma unroll
    for (int j = 0; j < 4; ++j) acc[i][j] = fzero;
#pragma unroll
  for (int ks = 0; ks < 8; ++ks) {
    if (ks < 7) {
#pragma unroll
      for (int ct = 0; ct < 4; ++ct)
        bn[ct] = *(const bf16x8*)(b1ptr + (size_t)(ks + 1) * 8192 + ct * 128);
    }
    bf16x8 a[2];
#pragma unroll
    for (int rt = 0; rt < 2; ++rt)
      a[rt] = *(const bf16x8*)&X[(rt * 16 + lr) * XPAD + ks * 32 + lq * 8];
#pragma unroll
    for (int ct = 0; ct < 4; ++ct)
#pragma unroll
      for (int rt = 0; rt < 2; ++rt) acc[rt][ct] = mfma16(a[rt], bc[ct], acc[rt][ct]);
#pragma unroll
    for (int ct = 0; ct < 4; ++ct) bc[ct] = bn[ct];
  }
#pragma unroll
  for (int ct = 0; ct < 4; ++ct) bn[ct] = *(const bf16x8*)(b2ptr + ct * 128);
  __syncthreads();
#pragma unroll
  for (int ct = 0; ct < 4; ++ct) {
    int c = col0 + ct * 16 + lr;
    float bb = b1[c];
#pragma unroll
    for (int rt = 0; rt < 2; ++rt)
#pragma unroll
      for (int r = 0; r < 4; ++r) {
        int row = rt * 16 + lq * 4 + r;
        X[row * XPAD + c] = f2bf(gelu_tanh(acc[rt][ct][r] + bb));
      }
  }
#pragma unroll
  for (int ct = 0; ct < 4; ++ct) bc[ct] = bn[ct];
  __syncthreads();
#pragma unroll
  for (int i = 0; i < 2; ++i)
#pragma unroll
    for (int j = 0; j < 4; ++j) acc[i][j] = fzero;
#pragma unroll
  for (int ks = 0; ks < 8; ++ks) {
    if (ks < 7) {
#pragma unroll
      for (int ct = 0; ct < 4; ++ct)
        bn[ct] = *(const bf16x8*)(b2ptr + (size_t)(ks + 1) * 8192 + ct * 128);
    }
    bf16x8 a[2];
#pragma unroll
    for (int rt = 0; rt < 2; ++rt)
      a[rt] = *(const bf16x8*)&X[(rt * 16 + lr) * XPAD + ks * 32 + lq * 8];
#pragma unroll
    for (int ct = 0; ct < 4; ++ct)
#pragma unroll
      for (int rt = 0; rt < 2; ++rt) acc[rt][ct] = mfma16(a[rt], bc[ct], acc[rt][ct]);
#pragma unroll
    for (int ct = 0; ct < 4; ++ct) bc[ct] = bn[ct];
  }
  float bb2[4];
#pragma unroll
  for (int ct = 0; ct < 4; ++ct) bb2[ct] = b2[col0 + ct * 16 + lr];
#pragma unroll
  for (int rt = 0; rt < 2; ++rt)
#pragma unroll
    for (int r = 0; r < 4; ++r) {
      int row = rt * 16 + lq * 4 + r;
      int grow = n0 + row;
      float p1 = 0.f, p2 = 0.f;
#pragma unroll
      for (int ct = 0; ct < 4; ++ct) {
        int c = col0 + ct * 16 + lr;
        float v = acc[rt][ct][r] + bb2[ct] + xin[(size_t)grow * 256 + c];
        x1[(size_t)grow * 256 + c] = v;
        acc[rt][ct][r] = v;
        p1 += v; p2 += v * v;
      }
#pragma unroll
      for (int o = 1; o < 16; o <<= 1) { p1 += __shfl_xor(p1, o); p2 += __shfl_xor(p2, o); }
      if (lr == 0) { S1[row][wv] = p1; S2[row][wv] = p2; }
    }
  __syncthreads();
  if (t < UROWS) {
    float s1 = S1[t][0] + S1[t][1] + S1[t][2] + S1[t][3];
    float s2 = S2[t][0] + S2[t][1] + S2[t][2] + S2[t][3];
    float mu = s1 * (1.0f / 256.0f);
    float var = s2 * (1.0f / 256.0f) - mu * mu;
    MUs[t] = mu;
    RSs[t] = rsqrtf(var + 1e-5f);
  }
  __syncthreads();
  float gv[4], bv[4];
#pragma unroll
  for (int ct = 0; ct < 4; ++ct) {
    int c = col0 + ct * 16 + lr;
    gv[ct] = lng[c]; bv[ct] = lnb[c];
  }
#pragma unroll
  for (int rt = 0; rt < 2; ++rt)
#pragma unroll
    for (int r = 0; r < 4; ++r) {
      int row = rt * 16 + lq * 4 + r;
      int grow = n0 + row;
      float mu = MUs[row], rs = RSs[row];
#pragma unroll
      for (int ct = 0; ct < 4; ++ct) {
        int c = col0 + ct * 16 + lr;
        gb[(size_t)grow * 256 + c] = f2bf((acc[rt][ct][r] - mu) * rs * gv[ct] + bv[ct]);
      }
    }
}

// ---------------- generic GEMM (+opt GELU / residual / fused-LN / QKV / merge) --
// MRG: A-staging reads the 4 attn partial-O f32 buffers + partial-l sums and
// writes the normalized bf16 fragment straight into LDS (replaces the separate
// attn_merge kernel + ctxb round-trip). Safe: op.o[2]=x2 rows are read in
// staging and written in the LNF epilogue by the SAME block only (disjoint
// row sets across blocks).
template <int ROWS, bool GELU_F, bool RES, bool OUTB, bool LNF, bool QKV, bool MRG>
__launch_bounds__(256, 2)
__global__ void gemm_kernel(const u16* __restrict__ A, int lda,
                            const u16* __restrict__ Wp, int K, int WCols,
                            const float* __restrict__ bias, float scale,
                            const float* __restrict__ res,
                            const float* __restrict__ lng, const float* __restrict__ lnb,
                            float* __restrict__ outf, u16* __restrict__ outh,
                            u16* __restrict__ outh2, u16* __restrict__ vtp, int ldo,
                            OPtrs op) {
  __shared__ __align__(16) u16 X[ROWS * XPAD];
  __shared__ float S1[LNF ? ROWS : 1][4], S2[LNF ? ROWS : 1][4];
  __shared__ float MUs[LNF ? ROWS : 1], RSs[LNF ? ROWS : 1];
  constexpr int RT = ROWS / 16;
  const f32x4 fzero = {0.f, 0.f, 0.f, 0.f};
  int t = threadIdx.x;
  int lane = t & 63, wv = t >> 6;
  int lr = lane & 15, lq = lane >> 4;
  int r0 = blockIdx.x * ROWS;
  int cb = blockIdx.y * 256;
  f32x4 acc[RT][4];
#pragma unroll
  for (int i = 0; i < RT; ++i)
#pragma unroll
    for (int j = 0; j < 4; ++j) acc[i][j] = fzero;
  const u16* bptr = Wp + ((size_t)lq * WCols + cb + wv * 64 + lr) * 8;
  bf16x8 bc[4], bn[4];
#pragma unroll
  for (int ct = 0; ct < 4; ++ct) bc[ct] = *(const bf16x8*)(bptr + ct * 128);
  int rr = t >> 5, c8 = (t & 31) * 8;
  for (int kc = 0; kc < K; kc += 256) {
    if (MRG) {
#pragma unroll
      for (int ii = 0; ii < ROWS / 8; ++ii) {
        int r = ii * 8 + rr;
        int grow = r0 + r;
        int head = c8 >> 5;
        int li = grow * 8 + head;
        float lsum = op.l[li] + op.l[32768 + li] + op.l[65536 + li] + op.l[98304 + li];
        float inv = 1.0f / lsum;
        u16 tmp[8];
#pragma unroll
        for (int j = 0; j < 8; j += 4) {
          float4 s0 = *(const float4*)(op.o[0] + (size_t)grow * 256 + c8 + j);
          float4 s1 = *(const float4*)(op.o[1] + (size_t)grow * 256 + c8 + j);
          float4 s2 = *(const float4*)(op.o[2] + (size_t)grow * 256 + c8 + j);
          float4 s3 = *(const float4*)(op.o[3] + (size_t)grow * 256 + c8 + j);
          tmp[j + 0] = f2bf((s0.x + s1.x + s2.x + s3.x) * inv);
          tmp[j + 1] = f2bf((s0.y + s1.y + s2.y + s3.y) * inv);
          tmp[j + 2] = f2bf((s0.z + s1.z + s2.z + s3.z) * inv);
          tmp[j + 3] = f2bf((s0.w + s1.w + s2.w + s3.w) * inv);
        }
        *(uint4*)&X[r * XPAD + c8] = *(const uint4*)tmp;
      }
    } else {
#pragma unroll
      for (int ii = 0; ii < ROWS / 8; ++ii) {
        int r = ii * 8 + rr;
        *(uint4*)&X[r * XPAD + c8] = *(const uint4*)(A + (size_t)(r0 + r) * lda + kc + c8);
      }
    }
    __syncthreads();
#pragma unroll
    for (int ks = 0; ks < 8; ++ks) {
      bool more = (ks < 7) || (kc + 256 < K);
      if (more) {
        size_t koff = (ks < 7) ? ((size_t)(kc >> 3) + (ks + 1) * 4) * WCols
                               : ((size_t)((kc + 256) >> 3)) * WCols;
#pragma unroll
        for (int ct = 0; ct < 4; ++ct)
          bn[ct] = *(const bf16x8*)(bptr + (koff + ct * 16) * 8);
      }
      bf16x8 a[RT];
#pragma unroll
      for (int rt = 0; rt < RT; ++rt)
        a[rt] = *(const bf16x8*)&X[(rt * 16 + lr) * XPAD + ks * 32 + lq * 8];
#pragma unroll
      for (int ct = 0; ct < 4; ++ct)
#pragma unroll
        for (int rt = 0; rt < RT; ++rt) acc[rt][ct] = mfma16(a[rt], bc[ct], acc[rt][ct]);
#pragma unroll
      for (int ct = 0; ct < 4; ++ct) bc[ct] = bn[ct];
    }
    __syncthreads();
  }
  if (QKV) {
    int y = blockIdx.y;
#pragma unroll
    for (int ct = 0; ct < 4; ++ct) {
      int c = cb + wv * 64 + ct * 16 + lr;
      float bb = bias[c];
#pragma unroll
      for (int rt = 0; rt < RT; ++rt)
#pragma unroll
        for (int r = 0; r < 4; ++r) {
          int row = r0 + rt * 16 + lq * 4 + r;
          u16 hv = f2bf(acc[rt][ct][r] + bb);
          if (y == 0)      outh[(size_t)row * 256 + c] = hv;
          else if (y == 1) outh2[(size_t)row * 256 + (c - 256)] = hv;
          else             vtp[(size_t)(c - 512) * 4096 + row] = hv;
        }
    }
  } else if (!LNF) {
#pragma unroll
    for (int ct = 0; ct < 4; ++ct) {
      int c = cb + wv * 64 + ct * 16 + lr;
      float bb = bias[c];
#pragma unroll
      for (int rt = 0; rt < RT; ++rt)
#pragma unroll
        for (int r = 0; r < 4; ++r) {
          int row = r0 + rt * 16 + lq * 4 + r;
          float v = (acc[rt][ct][r] + bb) * scale;
          if (GELU_F) v = gelu_tanh(v);
          if (RES) v += res[(size_t)row * 256 + c];
          if (OUTB) outh[(size_t)row * ldo + c] = f2bf(v);
          else      outf[(size_t)row * ldo + c] = v;
        }
    }
  } else {
    float bb[4];
#pragma unroll
    for (int ct = 0; ct < 4; ++ct) bb[ct] = bias[wv * 64 + ct * 16 + lr];
#pragma unroll
    for (int rt = 0; rt < RT; ++rt)
#pragma unroll
      for (int r = 0; r < 4; ++r) {
        int row = rt * 16 + lq * 4 + r;
        int grow = r0 + row;
        float p1 = 0.f, p2 = 0.f;
#pragma unroll
        for (int ct = 0; ct < 4; ++ct) {
          int c = wv * 64 + ct * 16 + lr;
          float v = acc[rt][ct][r] + bb[ct];
          if (RES) v += res[(size_t)grow * 256 + c];
          outf[(size_t)grow * 256 + c] = v;
          acc[rt][ct][r] = v;
          p1 += v; p2 += v * v;
        }
#pragma unroll
        for (int o = 1; o < 16; o <<= 1) { p1 += __shfl_xor(p1, o); p2 += __shfl_xor(p2, o); }
        if (lr == 0) { S1[row][wv] = p1; S2[row][wv] = p2; }
      }
    __syncthreads();
    if (t < ROWS) {
      float s1 = S1[t][0] + S1[t][1] + S1[t][2] + S1[t][3];
      float s2 = S2[t][0] + S2[t][1] + S2[t][2] + S2[t][3];
      float mu = s1 * (1.0f / 256.0f);
      float var = s2 * (1.0f / 256.0f) - mu * mu;
      MUs[t] = mu;
      RSs[t] = rsqrtf(var + 1e-5f);
    }
    __syncthreads();
    float gv[4], bv[4];
#pragma unroll
    for (int ct = 0; ct < 4; ++ct) {
      int c = wv * 64 + ct * 16 + lr;
      gv[ct] = lng[c]; bv[ct] = lnb[c];
    }
#pragma unroll
    for (int rt = 0; rt < RT; ++rt)
#pragma unroll
      for (int r = 0; r < 4; ++r) {
        int row = rt * 16 + lq * 4 + r;
        int grow = r0 + row;
        float mu = MUs[row], rs = RSs[row];
#pragma unroll
        for (int ct = 0; ct < 4; ++ct) {
          int c = wv * 64 + ct * 16 + lr;
          outh[(size_t)grow * ldo + c] = f2bf((acc[rt][ct][r] - mu) * rs * gv[ct] + bv[ct]);
        }
      }
  }
}

// ---------------- flash attention: key-split x4, 128-q blocks, partial O --------
// 512 threads = 8 waves x 16 q rows = 128 q rows per block; waves 0-3 stage K,
// waves 4-7 stage V (wave-uniform split, T14 one-tile-ahead prefetch kept).
// Per-tile serial cost amortizes over 2x the q rows vs the 64-q block (R11:
// -6us vs R9). LDS 42.5KB -> 3 blocks/CU.
__launch_bounds__(512, 3)
__global__ void attn_kernel(const u16* __restrict__ qb, const u16* __restrict__ kb,
                            const u16* __restrict__ vT, OPtrs op) {
  __shared__ u16 Kt[64 * 40];      // [key][d] pad 40
  __shared__ u16 Vt[32 * 72];      // [d][key] pad 72
  __shared__ float P32[8][1024];   // per-wave [16 q][64 key] f32, chunk-XOR swizzled
  const f32x4 fzero = {0.f, 0.f, 0.f, 0.f};
  int t = threadIdx.x;
  int lane = t & 63, wv = t >> 6;
  int lr = lane & 15, lq = lane >> 4;
  int head = blockIdx.y;
  int z = blockIdx.z;
  int q0 = blockIdx.x * 128 + wv * 16;
  int kbase = z * 1024;
  bf16x8 qf = *(const bf16x8*)(qb + (size_t)(q0 + lr) * 256 + head * 32 + lq * 8);
  f32x4 o0 = fzero, o1 = fzero;
  float l_i[4] = {0.f, 0.f, 0.f, 0.f};
  // staging roles: threads 0-255 own K (64 keys x 32 d), 256-511 own V (32 d x 64 keys)
  bool isK = (t < 256);
  int ts = t & 255;
  int kkey = ts >> 2, kdp = (ts & 3) * 8;      // K: [key][d]
  int vd = ts >> 3, vkc = (ts & 7) * 8;        // V: [d][key]
  const u16* vbase = vT + (size_t)(head * 32 + vd) * 4096;
  int psw = (lr >> 2) & 3;               // read-side swizzle key (row = lr)
  float* pw = &P32[wv][0];
  // T14: next tile staged in registers one iteration ahead.
  uint4 sreg;
  if (isK) sreg = *(const uint4*)(kb + (size_t)(kbase + kkey) * 256 + head * 32 + kdp);
  else     sreg = *(const uint4*)(vbase + kbase + vkc);
  for (int it = 0; it < 16; ++it) {
    __syncthreads();                     // prev tile's LDS consumers done
    if (isK) *(uint4*)&Kt[kkey * 40 + kdp] = sreg;
    else     *(uint4*)&Vt[vd * 72 + vkc]   = sreg;
    if (it < 15) {
      int kn = kbase + (it + 1) * 64;
      if (isK) sreg = *(const uint4*)(kb + (size_t)(kn + kkey) * 256 + head * 32 + kdp);
      else     sreg = *(const uint4*)(vbase + kn + vkc);
    }
    __syncthreads();
    f32x4 s[4];
#pragma unroll
    for (int ct = 0; ct < 4; ++ct) {
      bf16x8 bk = *(const bf16x8*)&Kt[(ct * 16 + lr) * 40 + lq * 8];
      s[ct] = mfma16(qf, bk, fzero);
    }
#pragma unroll
    for (int ct = 0; ct < 4; ++ct)
#pragma unroll
      for (int r = 0; r < 4; ++r) s[ct][r] = __expf(s[ct][r]);
#pragma unroll
    for (int r = 0; r < 4; ++r) {
      float ps = (s[0][r] + s[1][r]) + (s[2][r] + s[3][r]);
#pragma unroll
      for (int d = 1; d < 16; d <<= 1) ps += __shfl_xor(ps, d);
      l_i[r] += ps;
    }
    // P write: row=lq*4+r, col=ct*16+lr; chunk' = chunk ^ lq (conflict-free b32)
#pragma unroll
    for (int ct = 0; ct < 4; ++ct) {
      int col = ct * 16 + lr;
      int w = (((col >> 2) ^ lq) << 2) + (col & 3);
#pragma unroll
      for (int r = 0; r < 4; ++r) pw[(lq * 4 + r) * 64 + w] = s[ct][r];
    }
    // PV (P32 is wave-private: in-wave LDS ordering suffices, no barrier)
#pragma unroll
    for (int kp = 0; kp < 2; ++kp) {
      int cch = kp * 8 + lq * 2;         // chunk of col base kp*32+lq*8
      f32x4 f0 = *(const f32x4*)&pw[lr * 64 + ((cch ^ psw) << 2)];
      f32x4 f1 = *(const f32x4*)&pw[lr * 64 + (((cch + 1) ^ psw) << 2)];
      bf16x8 pa;
#pragma unroll
      for (int j = 0; j < 4; ++j) { pa[j] = (__bf16)f0[j]; pa[j + 4] = (__bf16)f1[j]; }
      bf16x8 v0 = *(const bf16x8*)&Vt[lr * 72 + kp * 32 + lq * 8];
      bf16x8 v1 = *(const bf16x8*)&Vt[(16 + lr) * 72 + kp * 32 + lq * 8];
      o0 = mfma16(pa, v0, o0);
      o1 = mfma16(pa, v1, o1);
    }
  }
  float* ob = op.o[z];
  float* lp = op.l + z * 32768;
#pragma unroll
  for (int r = 0; r < 4; ++r) {
    int row = q0 + lq * 4 + r;
    ob[(size_t)row * 256 + head * 32 + lr]      = o0[r];
    ob[(size_t)row * 256 + head * 32 + 16 + lr] = o1[r];
    if (lr == 0) lp[row * 8 + head] = l_i[r];
  }
}

// ---------------- host launch ---------------------------------------------------
extern "C" void kernel_launch(void* const* d_in, const int* in_sizes, int n_in,
                              void* d_out, int out_size, void* d_ws, size_t ws_size,
                              hipStream_t stream) {
  const float* x         = (const float*)d_in[0];
  const int*   ei        = (const int*)d_in[1];
  const float* edge_attr = (const float*)d_in[2];
  const float* eps       = (const float*)d_in[3];
  const float* e_w1 = (const float*)d_in[4];
  const float* e_b1 = (const float*)d_in[5];
  const float* e_w2 = (const float*)d_in[6];
  const float* e_b2 = (const float*)d_in[7];
  const float* u_w1 = (const float*)d_in[8];
  const float* u_b1 = (const float*)d_in[9];
  const float* u_w2 = (const float*)d_in[10];
  const float* u_b2 = (const float*)d_in[11];
  const float* ln_local_g  = (const float*)d_in[12];
  const float* ln_local_b  = (const float*)d_in[13];
  const float* ln_global_g = (const float*)d_in[14];
  const float* ln_global_b = (const float*)d_in[15];
  const float* ln_ffn_g    = (const float*)d_in[16];
  const float* ln_ffn_b    = (const float*)d_in[17];
  const float* wq = (const float*)d_in[18];
  const float* wk = (const float*)d_in[19];
  const float* wv = (const float*)d_in[20];
  const float* bq = (const float*)d_in[21];
  const float* bk = (const float*)d_in[22];
  const float* bv = (const float*)d_in[23];
  const float* wo = (const float*)d_in[24];
  const float* bo = (const float*)d_in[25];
  const float* f_w1 = (const float*)d_in[26];
  const float* f_b1 = (const float*)d_in[27];
  const float* f_w2 = (const float*)d_in[28];
  const float* f_b2 = (const float*)d_in[29];

  char* ws = (char*)d_ws;
  u16*   WP      = (u16*)(ws + 0);                         // 2 MB
  float* agg     = (float*)(ws + (2u  << 20));             // 4 MB
  int*   deg     = (int*)(ws + (6u  << 20));               // 16 KB
  int*   cnt     = (int*)(ws + (6u  << 20) + (16u << 10)); // 16 KB
  int*   offs    = (int*)(ws + (6u  << 20) + (32u << 10)); // 16.4 KB
  float* qkvbias = (float*)(ws + (6u << 20) + (64u << 10));// 3 KB
  float* hf      = (float*)(ws + (7u  << 20));             // 4 MB
  float* x1      = (float*)(ws + (11u << 20));             // 4 MB
  u16*   gb      = (u16*)(ws + (15u << 20));               // 2 MB
  u16*   qbuf    = (u16*)(ws + (17u << 20));               // 2 MB
  u16*   kbuf    = (u16*)(ws + (19u << 20));               // 2 MB
  u16*   vTb     = (u16*)(ws + (21u << 20));               // 2 MB [256][4096]
  float* x2      = (float*)(ws + (25u << 20));             // 4 MB
  u16*   yb      = (u16*)(ws + (29u << 20));               // 2 MB
  u16*   hid     = (u16*)(ws + (31u << 20));               // 8 MB
  int*   eperm   = (int*)(ws + (39u << 20));               // 512 KB
  int*   dst_s   = (int*)(ws + (39u << 20) + (512u << 10));// 512 KB
  int*   src_s   = (int*)(ws + (40u << 20));               // 512 KB
  u16*   hb      = (u16*)(ws + (40u << 20) + (512u << 10));// 2 MB

  const size_t O_EW1 = 0, O_EW2 = 65536, O_UW1 = 131072, O_UW2 = 196608,
               O_QKV = 262144, O_WO = 458752, O_FW1 = 524288, O_FW2 = 786432;
  const float qscale = 0.17677669529663687f;  // 1/sqrt(32)

  hipMemsetAsync(agg, 0, (4u << 20) + (32u << 10), stream);

  // Partial-O buffers reuse regions dead during attention:
  //   agg (dead after update), hf (dead after update), x2/yb/hid (written later).
  OPtrs op;
  op.o[0] = agg;
  op.o[1] = hf;
  op.o[2] = x2;
  op.o[3] = (float*)(ws + (31u << 20));   // head of hid region (4 MB of 8)
  op.l    = (float*)(ws + (29u << 20));   // yb region (needs 512 KB)

  WPtrs wp;
  wp.p[0] = e_w1; wp.p[1] = e_w2; wp.p[2] = u_w1; wp.p[3] = u_w2;
  wp.p[4] = wq;   wp.p[5] = wk;   wp.p[6] = wv;   wp.p[7] = wo;
  wp.p[8] = f_w1; wp.p[9] = f_w2;
  setup_kernel<<<1025, 256, 0, stream>>>(wp, WP, qscale, ei, deg, bq, bk, bv, qkvbias);
  // LN (1024 blocks x 4 rows) + scan (block 1024) run concurrently.
  ln_scan_kernel<<<1025, 1024, 0, stream>>>(x, ln_local_g, ln_local_b, hf, hb, deg, offs);
  scatter_kernel<<<512, 256, 0, stream>>>(ei, offs, cnt, eperm, dst_s, src_s);

  edge_kernel<<<N_EDGES / 128, 512, 0, stream>>>(hb, edge_attr, eperm, src_s, dst_s, offs,
                                                 WP + O_EW1, e_b1, WP + O_EW2, e_b2, agg);

  update_kernel<<<N_NODES / UROWS, 256, 0, stream>>>(hf, agg, eps, x,
                                                     WP + O_UW1, u_b1, WP + O_UW2, u_b2,
                                                     ln_global_g, ln_global_b, x1, gb);

  // QKV: y=0 -> qbuf, y=1 -> kbuf, y=2 -> vT (transposed). ROWS=32 -> 384 blocks.
  gemm_kernel<32, false, false, true, false, true, false><<<dim3(128, 3), 256, 0, stream>>>(
      gb, 256, WP + O_QKV, 256, 768, qkvbias, 1.0f, nullptr, nullptr, nullptr,
      nullptr, qbuf, kbuf, vTb, 256, op);

  attn_kernel<<<dim3(32, 8, 4), 512, 0, stream>>>(qbuf, kbuf, vTb, op);

  // x2 = x1 + merge(O_z)/merge(l_z) @ wo + bo ; yb = LN_ffn(x2). MRG staging
  // replaces the separate attn_merge kernel + ctxb round-trip.
  gemm_kernel<16, false, true, false, true, false, true><<<dim3(256, 1), 256, 0, stream>>>(
      nullptr, 256, WP + O_WO, 256, 256, bo, 1.0f, x1, ln_ffn_g, ln_ffn_b, x2, yb,
      nullptr, nullptr, 256, op);

  // FFN1: ROWS=32 -> dim3(128,4)=512 blocks.
  gemm_kernel<32, true, false, true, false, false, false><<<dim3(128, 4), 256, 0, stream>>>(
      yb, 256, WP + O_FW1, 256, 1024, f_b1, 1.0f, nullptr, nullptr, nullptr,
      nullptr, hid, nullptr, nullptr, 1024, op);

  // FFN2: ROWS=16 -> 256 blocks.
  gemm_kernel<16, false, true, false, false, false, false><<<dim3(256, 1), 256, 0, stream>>>(
      hid, 1024, WP + O_FW2, 1024, 256, f_b2, 1.0f, x2, nullptr, nullptr,
      (float*)d_out, nullptr, nullptr, nullptr, 256, op);
}